// Round 18
// baseline (383.848 us; speedup 1.0000x reference)
//
#include <hip/hip_runtime.h>

typedef unsigned short ushort_t;
typedef __bf16 bf16x8 __attribute__((ext_vector_type(8)));
typedef float f32x4 __attribute__((ext_vector_type(4)));

#define BB 4
#define TT 2048
#define DIMD 1024
#define NH 16
#define DK 64
#define MROWS (BB * TT)   /* 8192 */
#define NQKV (3 * DIMD)   /* 3072 */

__device__ __forceinline__ ushort_t f2b(float f) {
  __bf16 h = (__bf16)f;
  union { __bf16 h; ushort_t u; } c; c.h = h; return c.u;
}
__device__ __forceinline__ float fexp2(float x) {   // v_exp_f32: 2^x
  float r;
  asm("v_exp_f32 %0, %1" : "=v"(r) : "v"(x));
  return r;
}

// async global->LDS, 16B per lane; LDS dest is wave-uniform base + lane*16
__device__ __forceinline__ void gload_lds16(const void* g, void* l) {
  __builtin_amdgcn_global_load_lds(
      (const __attribute__((address_space(1))) void*)g,
      (__attribute__((address_space(3))) void*)l,
      16, 0, 0);
}

// f32 -> bf16 downcast, 8 elems/thread (n % 2048 == 0)
__global__ __launch_bounds__(256) void cast_f32_bf16(
    const float* __restrict__ in, ushort_t* __restrict__ out, int n)
{
  const int i = (blockIdx.x * 256 + threadIdx.x) * 8;
  if (i >= n) return;
  float4 a = *(const float4*)(in + i);
  float4 b = *(const float4*)(in + i + 4);
  ushort_t o[8];
  o[0] = f2b(a.x); o[1] = f2b(a.y); o[2] = f2b(a.z); o[3] = f2b(a.w);
  o[4] = f2b(b.x); o[5] = f2b(b.y); o[6] = f2b(b.z); o[7] = f2b(b.w);
  *(uint4*)(out + i) = *(const uint4*)o;
}

// ---------------- GEMM 128x256: triple-buffer, 1 barrier/K-tile (round 14) --
template <bool OUT_F32>
__global__ __launch_bounds__(512, 4) void gemm_bt_pipe(
    const ushort_t* __restrict__ A, const ushort_t* __restrict__ W,
    const float* __restrict__ bias, void* __restrict__ Cp,
    int M, int N, int K)
{
  __shared__ __align__(16) ushort_t As[3][128 * 32];
  __shared__ __align__(16) ushort_t Bs[3][256 * 32];

  const int tid = threadIdx.x;
  const int wave = tid >> 6, lane = tid & 63;
  const int x = blockIdx.x & 7, j = blockIdx.x >> 3;   // XCD id, local index
  const int bm = (x << 3) | (j & 7);
  const int bn = j >> 3;
  const int row0 = bm << 7, col0 = bn << 8;
  const int wm = (wave >> 2) << 6;
  const int wn = (wave & 3) << 6;
  const int fr = lane & 15;
  const int g  = lane >> 4;
  const int g4 = g << 2;
  const int csw = (g ^ (fr >> 2)) << 3;

  const int srow = lane >> 2;
  const int scol = ((lane & 3) ^ ((lane >> 4) & 3)) << 3;
  const int lbase = wave << 9;

  const ushort_t* Ag  = A + (size_t)(row0 + (wave << 4) + srow) * K + scol;
  const ushort_t* Wg0 = W + (size_t)(col0 + (wave << 4) + srow) * K + scol;
  const ushort_t* Wg1 = Wg0 + (size_t)128 * K;

#define STAGE_P(kt, buf)                                                      \
  {                                                                           \
    const size_t _k = (size_t)(kt) << 5;                                      \
    gload_lds16(Ag + _k,  &As[buf][lbase]);                                   \
    gload_lds16(Wg0 + _k, &Bs[buf][lbase]);                                   \
    gload_lds16(Wg1 + _k, &Bs[buf][4096 + lbase]);                            \
  }

  const int NT = K >> 5;
  STAGE_P(0, 0);
  STAGE_P(1, 1);

  f32x4 acc[4][4] = {};
  int cr = 0, st = 2;

  for (int t = 0; t < NT; ++t) {
    if (t + 1 < NT) asm volatile("s_waitcnt vmcnt(3)" ::: "memory");
    else            asm volatile("s_waitcnt vmcnt(0)" ::: "memory");
    __builtin_amdgcn_s_barrier();

    const ushort_t* as_ = As[cr];
    const ushort_t* bs_ = Bs[cr];
    bf16x8 af0 = *(const bf16x8*)&as_[(wm +      fr) * 32 + csw];
    bf16x8 af1 = *(const bf16x8*)&as_[(wm + 16 + fr) * 32 + csw];
    bf16x8 bw0 = *(const bf16x8*)&bs_[(wn +      fr) * 32 + csw];
    bf16x8 bw1 = *(const bf16x8*)&bs_[(wn + 16 + fr) * 32 + csw];
    bf16x8 bw2 = *(const bf16x8*)&bs_[(wn + 32 + fr) * 32 + csw];
    bf16x8 bw3 = *(const bf16x8*)&bs_[(wn + 48 + fr) * 32 + csw];
    if (t + 2 < NT) STAGE_P(t + 2, st);
    asm volatile("s_waitcnt lgkmcnt(0)" ::: "memory");
    __builtin_amdgcn_sched_barrier(0);
    __builtin_amdgcn_s_setprio(1);
    acc[0][0] = __builtin_amdgcn_mfma_f32_16x16x32_bf16(af0, bw0, acc[0][0], 0, 0, 0);
    acc[0][1] = __builtin_amdgcn_mfma_f32_16x16x32_bf16(af0, bw1, acc[0][1], 0, 0, 0);
    acc[0][2] = __builtin_amdgcn_mfma_f32_16x16x32_bf16(af0, bw2, acc[0][2], 0, 0, 0);
    acc[0][3] = __builtin_amdgcn_mfma_f32_16x16x32_bf16(af0, bw3, acc[0][3], 0, 0, 0);
    acc[1][0] = __builtin_amdgcn_mfma_f32_16x16x32_bf16(af1, bw0, acc[1][0], 0, 0, 0);
    acc[1][1] = __builtin_amdgcn_mfma_f32_16x16x32_bf16(af1, bw1, acc[1][1], 0, 0, 0);
    acc[1][2] = __builtin_amdgcn_mfma_f32_16x16x32_bf16(af1, bw2, acc[1][2], 0, 0, 0);
    acc[1][3] = __builtin_amdgcn_mfma_f32_16x16x32_bf16(af1, bw3, acc[1][3], 0, 0, 0);
    __builtin_amdgcn_s_setprio(0);

    bf16x8 af2 = *(const bf16x8*)&as_[(wm + 32 + fr) * 32 + csw];
    bf16x8 af3 = *(const bf16x8*)&as_[(wm + 48 + fr) * 32 + csw];
    asm volatile("s_waitcnt lgkmcnt(0)" ::: "memory");
    __builtin_amdgcn_sched_barrier(0);
    __builtin_amdgcn_s_setprio(1);
    acc[2][0] = __builtin_amdgcn_mfma_f32_16x16x32_bf16(af2, bw0, acc[2][0], 0, 0, 0);
    acc[2][1] = __builtin_amdgcn_mfma_f32_16x16x32_bf16(af2, bw1, acc[2][1], 0, 0, 0);
    acc[2][2] = __builtin_amdgcn_mfma_f32_16x16x32_bf16(af2, bw2, acc[2][2], 0, 0, 0);
    acc[2][3] = __builtin_amdgcn_mfma_f32_16x16x32_bf16(af2, bw3, acc[2][3], 0, 0, 0);
    acc[3][0] = __builtin_amdgcn_mfma_f32_16x16x32_bf16(af3, bw0, acc[3][0], 0, 0, 0);
    acc[3][1] = __builtin_amdgcn_mfma_f32_16x16x32_bf16(af3, bw1, acc[3][1], 0, 0, 0);
    acc[3][2] = __builtin_amdgcn_mfma_f32_16x16x32_bf16(af3, bw2, acc[3][2], 0, 0, 0);
    acc[3][3] = __builtin_amdgcn_mfma_f32_16x16x32_bf16(af3, bw3, acc[3][3], 0, 0, 0);
    __builtin_amdgcn_s_setprio(0);

    ++cr; if (cr == 3) cr = 0;
    ++st; if (st == 3) st = 0;
  }
#undef STAGE_P

#pragma unroll
  for (int jj = 0; jj < 4; ++jj) {
    const int col = col0 + wn + (jj << 4) + fr;
    const float bv = bias[col];
#pragma unroll
    for (int i = 0; i < 4; ++i)
#pragma unroll
      for (int r = 0; r < 4; ++r) {
        const size_t row = (size_t)(row0 + wm + (i << 4) + g4 + r);
        if constexpr (OUT_F32)
          ((float*)Cp)[row * (size_t)N + col] = acc[i][jj][r] + bv;
        else
          ((ushort_t*)Cp)[row * (size_t)N + col] = f2b(acc[i][jj][r] + bv);
      }
  }
}

// ---------------- GEMM 128x128 (round-11 verified; for out-proj) ------------
template <bool OUT_F32>
__global__ __launch_bounds__(256) void gemm_bt_bias(
    const ushort_t* __restrict__ A, const ushort_t* __restrict__ W,
    const float* __restrict__ bias, void* __restrict__ Cp,
    int M, int N, int K)
{
  __shared__ __align__(16) ushort_t As[128 * 32];
  __shared__ __align__(16) ushort_t Bs[128 * 32];

  const int tid = threadIdx.x;
  const int wave = tid >> 6, lane = tid & 63;
  const int tiles_n = N >> 7;
  const int bm = blockIdx.x / tiles_n, bn = blockIdx.x % tiles_n;
  const int row0 = bm << 7, col0 = bn << 7;
  const int wm = (wave >> 1) << 6;
  const int wn = (wave & 1) << 6;
  const int fr = lane & 15;
  const int fk = (lane >> 4) << 3;
  const int g4 = (lane >> 4) << 2;

  const int sr = lane >> 2;
  const int csw = fk ^ (((fr >> 1) & 3) << 3);

  f32x4 acc[4][4] = {};

  for (int k0 = 0; k0 < K; k0 += 32) {
    __syncthreads();
#pragma unroll
    for (int p = 0; p < 2; ++p) {
      const int e = (wave << 9) + (p << 11);
      const int r = (e >> 5) + sr;
      const int c = ((lane & 3) << 3) ^ (((r >> 1) & 3) << 3);
      gload_lds16(A + (size_t)(row0 + r) * K + (k0 + c), As + e);
      gload_lds16(W + (size_t)(col0 + r) * K + (k0 + c), Bs + e);
    }
    __syncthreads();

    bf16x8 af[4], bw[4];
#pragma unroll
    for (int i = 0; i < 4; ++i) {
      af[i] = *(const bf16x8*)&As[(wm + (i << 4) + fr) * 32 + csw];
      bw[i] = *(const bf16x8*)&Bs[(wn + (i << 4) + fr) * 32 + csw];
    }
#pragma unroll
    for (int mi = 0; mi < 4; ++mi)
#pragma unroll
      for (int ni = 0; ni < 4; ++ni)
        acc[mi][ni] = __builtin_amdgcn_mfma_f32_16x16x32_bf16(af[mi], bw[ni], acc[mi][ni], 0, 0, 0);
  }

#pragma unroll
  for (int ni = 0; ni < 4; ++ni) {
    const int col = col0 + wn + (ni << 4) + fr;
    const float bv = bias[col];
#pragma unroll
    for (int mi = 0; mi < 4; ++mi)
#pragma unroll
      for (int r = 0; r < 4; ++r) {
        const size_t row = (size_t)(row0 + wm + (mi << 4) + g4 + r);
        if constexpr (OUT_F32)
          ((float*)Cp)[row * (size_t)N + col] = acc[mi][ni][r] + bv;
        else
          ((ushort_t*)Cp)[row * (size_t)N + col] = f2b(acc[mi][ni][r] + bv);
      }
  }
}

// ---------------- Flash attention: PAIR-FUSED, shared K/V staging -----------
// 1024 blocks, 256 thr / 4 waves. Block handles BOTH tiles {qa=bq, qb=31-bq}
// in ONE kt-loop (kt=0..qb): K/V staged once; tile A active while kt<=qa.
// Total MFMA steps/block uniform (33). Shared bk/bv fragments feed both
// tiles (LDS reads halved). LDS = Ks 16KB + U 24KB = 40KB -> 4 blocks/CU.
// Union: Qs[0,16KB) prologue-only aliases Vt[0,8KB)+PsB[8,16KB); PsA above.
#define C1 0.18033688011112042f   /* 0.125 * log2(e) */
__global__ __launch_bounds__(256, 4) void attn_fused(
    const ushort_t* __restrict__ qkv, ushort_t* __restrict__ ctx)
{
  __shared__ __align__(16) ushort_t Ks[2][64 * 64];   // 16KB
  __shared__ __align__(16) ushort_t U[12288];         // 24KB
  ushort_t* const Vt  = U;             // [64][64] hh-swizzled
  ushort_t* const PsB = U + 4096;      // 4 waves x 1024
  ushort_t* const PsA = U + 8192;      // 4 waves x 1024
  ushort_t* const Qs  = U;             // prologue: 2 tiles x 64x64 (16KB)

  const int tid = threadIdx.x, wave = tid >> 6, lane = tid & 63;
  const int fr = lane & 15;
  const int g  = lane >> 4;
  const int fk = g << 3;
  const int g4 = g << 2;

  const int bid = blockIdx.x;
  const int bq  = (bid >> 3) & 15;                    // pair index 0..15
  const int G   = (bid & 7) | ((bid >> 7) << 3);      // (b,h) group
  const int h   = G & 15;
  const int b   = G >> 4;

  const int srl = lane >> 3;
  const int scc = ((lane & 7) ^ srl) << 3;
  const int vr  = tid >> 2;            // V row 0..63
  const int vc  = (tid & 3) << 4;      // V col base {0,16,32,48}
  const int rsw = (fr & 7) << 3;

  const int qa = bq, qb = 31 - bq;     // qa <= 15 < 16 <= qb

  const ushort_t* Kg = qkv + (size_t)b * TT * NQKV + DIMD + h * DK;
  const ushort_t* Vg = qkv + (size_t)b * TT * NQKV + 2 * DIMD + h * DK;
  const size_t qrow0A = (size_t)b * TT + (size_t)qa * 64;
  const size_t qrow0B = (size_t)b * TT + (size_t)qb * 64;

  // prologue: V(0) regs + QA,QB,K(0) DMA
  uint4 va = *(const uint4*)(Vg + (size_t)vr * NQKV + vc);
  uint4 vb = *(const uint4*)(Vg + (size_t)vr * NQKV + vc + 8);
  const ushort_t* QgA = qkv + qrow0A * NQKV + h * DK;
  const ushort_t* QgB = qkv + qrow0B * NQKV + h * DK;
#pragma unroll
  for (int p = 0; p < 2; ++p) {
    const int e  = (wave << 10) + (p << 9);
    const int rr = (wave << 4) + (p << 3) + srl;
    gload_lds16(QgA + (size_t)rr * NQKV + scc, Qs + e);
    gload_lds16(QgB + (size_t)rr * NQKV + scc, Qs + 4096 + e);
    gload_lds16(Kg  + (size_t)rr * NQKV + scc, Ks[0] + e);
  }
  asm volatile("s_waitcnt vmcnt(0)" ::: "memory");
  __syncthreads();

  bf16x8 aqrA[2], aqrB[2];
#pragma unroll
  for (int ks = 0; ks < 2; ++ks) {
    aqrA[ks] = *(const bf16x8*)&Qs[((wave << 4) + fr) * 64 + (((ks << 5) + fk) ^ rsw)];
    aqrB[ks] = *(const bf16x8*)&Qs[4096 + ((wave << 4) + fr) * 64 + (((ks << 5) + fk) ^ rsw)];
  }
  __syncthreads();   // hoists done before Vt/Ps (union) writes

  const int qrowA = (qa << 6) + (wave << 4) + fr;
  const int qrowB = (qb << 6) + (wave << 4) + fr;
  float mA = -1e30f, lA = 0.f, mB = -1e30f, lB = 0.f;
  f32x4 oA[4] = {}, oB[4] = {};
  int cur = 0;

  for (int kt = 0; kt <= qb; ++kt) {
    {  // scatter V(kt) regs -> Vt (hh-swizzled), 16 elems/thread
      __align__(16) ushort_t tmp[16];
      *(uint4*)&tmp[0] = va;
      *(uint4*)&tmp[8] = vb;
#pragma unroll
      for (int jj = 0; jj < 16; ++jj) {
        const int d  = vc + jj;
        const int hh = (d & 7) ^ ((d >> 3) & 7);
        Vt[d * 64 + (vr ^ (hh << 3))] = tmp[jj];
      }
    }
    if (kt < qb) {   // prefetch K(kt+1) DMA + V(kt+1) regs
      const size_t krow = (size_t)(kt + 1) << 6;
#pragma unroll
      for (int p = 0; p < 2; ++p) {
        const int e  = (wave << 10) + (p << 9);
        const int rr = (wave << 4) + (p << 3) + srl;
        gload_lds16(Kg + (krow + rr) * NQKV + scc, Ks[cur ^ 1] + e);
      }
      va = *(const uint4*)(Vg + (krow + vr) * NQKV + vc);
      vb = *(const uint4*)(Vg + (krow + vr) * NQKV + vc + 8);
    }
    asm volatile("s_waitcnt lgkmcnt(0)" ::: "memory");   // scatter drained
    __builtin_amdgcn_s_barrier();                        // no vmcnt drain

    const bool doA = (kt <= qa);   // block-uniform

    // QK both tiles: shared bk fragment
    f32x4 sA[4] = {}, sB[4] = {};
    __builtin_amdgcn_s_setprio(1);
#pragma unroll
    for (int ks = 0; ks < 2; ++ks)
#pragma unroll
      for (int ni = 0; ni < 4; ++ni) {
        const bf16x8 bk = *(const bf16x8*)&Ks[cur][((ni << 4) + fr) * 64 + (((ks << 5) + fk) ^ rsw)];
        sB[ni] = __builtin_amdgcn_mfma_f32_16x16x32_bf16(bk, aqrB[ks], sB[ni], 0, 0, 0);
        if (doA)
          sA[ni] = __builtin_amdgcn_mfma_f32_16x16x32_bf16(bk, aqrA[ks], sA[ni], 0, 0, 0);
      }
    __builtin_amdgcn_s_setprio(0);

    // ---- softmax tile B ----
    {
      if (kt == qb) {
        const int kb = kt << 6;
#pragma unroll
        for (int ni = 0; ni < 4; ++ni)
#pragma unroll
          for (int r = 0; r < 4; ++r) {
            const int kc = kb + (ni << 4) + g4 + r;
            if (kc > qrowB) sB[ni][r] = -1e30f;
          }
      }
      float rm = -1e30f;
#pragma unroll
      for (int ni = 0; ni < 4; ++ni)
        rm = fmaxf(rm, fmaxf(fmaxf(sB[ni][0], sB[ni][1]), fmaxf(sB[ni][2], sB[ni][3])));
      rm = fmaxf(rm, __shfl_xor(rm, 16, 64));
      rm = fmaxf(rm, __shfl_xor(rm, 32, 64));
      if (__any(rm > mB + 64.f)) {
        const float mn = fmaxf(mB, rm);
        const float corr = fexp2((mB - mn) * C1);
        mB = mn; lB *= corr;
#pragma unroll
        for (int ni = 0; ni < 4; ++ni) oB[ni] *= corr;
      }
      const float nm2 = -mB * C1;
      float rs = 0.f;
#pragma unroll
      for (int ni = 0; ni < 4; ++ni)
#pragma unroll
        for (int r = 0; r < 4; ++r) {
          const float pe = fexp2(fmaf(sB[ni][r], C1, nm2));
          sB[ni][r] = pe;
          rs += pe;
        }
      rs += __shfl_xor(rs, 16, 64);
      rs += __shfl_xor(rs, 32, 64);
      lB += rs;
#pragma unroll
      for (int ni = 0; ni < 4; ++ni) {
        ushort_t o4[4];
#pragma unroll
        for (int r = 0; r < 4; ++r) o4[r] = f2b(sB[ni][r]);
        *(uint2*)&PsB[(wave << 10) + fr * 64 + (((ni << 4) + g4) ^ rsw)] = *(const uint2*)o4;
      }
    }

    // ---- softmax tile A (only while kt <= qa) ----
    if (doA) {
      if (kt == qa) {
        const int kb = kt << 6;
#pragma unroll
        for (int ni = 0; ni < 4; ++ni)
#pragma unroll
          for (int r = 0; r < 4; ++r) {
            const int kc = kb + (ni << 4) + g4 + r;
            if (kc > qrowA) sA[ni][r] = -1e30f;
          }
      }
      float rm = -1e30f;
#pragma unroll
      for (int ni = 0; ni < 4; ++ni)
        rm = fmaxf(rm, fmaxf(fmaxf(sA[ni][0], sA[ni][1]), fmaxf(sA[ni][2], sA[ni][3])));
      rm = fmaxf(rm, __shfl_xor(rm, 16, 64));
      rm = fmaxf(rm, __shfl_xor(rm, 32, 64));
      if (__any(rm > mA + 64.f)) {
        const float mn = fmaxf(mA, rm);
        const float corr = fexp2((mA - mn) * C1);
        mA = mn; lA *= corr;
#pragma unroll
        for (int ni = 0; ni < 4; ++ni) oA[ni] *= corr;
      }
      const float nm2 = -mA * C1;
      float rs = 0.f;
#pragma unroll
      for (int ni = 0; ni < 4; ++ni)
#pragma unroll
        for (int r = 0; r < 4; ++r) {
          const float pe = fexp2(fmaf(sA[ni][r], C1, nm2));
          sA[ni][r] = pe;
          rs += pe;
        }
      rs += __shfl_xor(rs, 16, 64);
      rs += __shfl_xor(rs, 32, 64);
      lA += rs;
#pragma unroll
      for (int ni = 0; ni < 4; ++ni) {
        ushort_t o4[4];
#pragma unroll
        for (int r = 0; r < 4; ++r) o4[r] = f2b(sA[ni][r]);
        *(uint2*)&PsA[(wave << 10) + fr * 64 + (((ni << 4) + g4) ^ rsw)] = *(const uint2*)o4;
      }
    }

    asm volatile("s_waitcnt lgkmcnt(0)" ::: "memory");
    __builtin_amdgcn_sched_barrier(0);

    // batched PV: shared bv fragment feeds both tiles
    __builtin_amdgcn_s_setprio(1);
#pragma unroll
    for (int ks = 0; ks < 2; ++ks) {
      const bf16x8 apB = *(const bf16x8*)&PsB[(wave << 10) + fr * 64 + (((ks << 5) + fk) ^ rsw)];
      bf16x8 apA{};
      if (doA)
        apA = *(const bf16x8*)&PsA[(wave << 10) + fr * 64 + (((ks << 5) + fk) ^ rsw)];
#pragma unroll
      for (int ni = 0; ni < 4; ++ni) {
        const int hh = (fr & 7) ^ ((2 * ni + (fr >> 3)) & 7);
        const bf16x8 bv = *(const bf16x8*)&Vt[((ni << 4) + fr) * 64 + (((ks << 5) + fk) ^ (hh << 3))];
        oB[ni] = __builtin_amdgcn_mfma_f32_16x16x32_bf16(bv, apB, oB[ni], 0, 0, 0);
        if (doA)
          oA[ni] = __builtin_amdgcn_mfma_f32_16x16x32_bf16(bv, apA, oA[ni], 0, 0, 0);
      }
    }
    __builtin_amdgcn_s_setprio(0);

    if (kt < qb) {
      asm volatile("s_waitcnt vmcnt(0)" ::: "memory");   // K-DMA(kt+1)+va landed
      __syncthreads();                                   // Vt/Ks readers done
    }
    cur ^= 1;
  }

  // epilogues
  {
    const float inv = 1.f / lB;
    ushort_t* crow = ctx + (qrow0B + (wave << 4) + fr) * DIMD + h * DK;
#pragma unroll
    for (int ni = 0; ni < 4; ++ni) {
      ushort_t o4[4];
#pragma unroll
      for (int r = 0; r < 4; ++r) o4[r] = f2b(oB[ni][r] * inv);
      *(uint2*)&crow[(ni << 4) + g4] = *(const uint2*)o4;
    }
  }
  {
    const float inv = 1.f / lA;
    ushort_t* crow = ctx + (qrow0A + (wave << 4) + fr) * DIMD + h * DK;
#pragma unroll
    for (int ni = 0; ni < 4; ++ni) {
      ushort_t o4[4];
#pragma unroll
      for (int r = 0; r < 4; ++r) o4[r] = f2b(oA[ni][r] * inv);
      *(uint2*)&crow[(ni << 4) + g4] = *(const uint2*)o4;
    }
  }
}

extern "C" void kernel_launch(void* const* d_in, const int* in_sizes, int n_in,
                              void* d_out, int out_size, void* d_ws, size_t ws_size,
                              hipStream_t stream) {
  const float* x     = (const float*)d_in[0];
  const float* w_qkv = (const float*)d_in[1];
  const float* b_qkv = (const float*)d_in[2];
  const float* w_out = (const float*)d_in[3];
  const float* b_out = (const float*)d_in[4];

  const size_t need = 36u * 1024 * 1024 * sizeof(ushort_t);   // 72 MiB
  if (ws_size < need) return;

  ushort_t* qkv = (ushort_t*)d_ws;
  ushort_t* xb  = qkv + (size_t)MROWS * NQKV;
  ushort_t* wqb = xb  + (size_t)MROWS * DIMD;
  ushort_t* wob = wqb + (size_t)NQKV * DIMD;
  ushort_t* ctx = xb;
  float*    out = (float*)d_out;

  cast_f32_bf16<<<dim3(MROWS * DIMD / 2048), dim3(256), 0, stream>>>(x, xb, MROWS * DIMD);
  cast_f32_bf16<<<dim3(NQKV * DIMD / 2048), dim3(256), 0, stream>>>(w_qkv, wqb, NQKV * DIMD);
  cast_f32_bf16<<<dim3(DIMD * DIMD / 2048), dim3(256), 0, stream>>>(w_out, wob, DIMD * DIMD);
  // 1) QKV projection — 128x256 triple-buffer pipeline (grid 768)
  gemm_bt_pipe<false><<<dim3((MROWS / 128) * (NQKV / 256)), dim3(512), 0, stream>>>(
      xb, wqb, b_qkv, (void*)qkv, MROWS, NQKV, DIMD);
  // 2) causal flash attention — 1024 pair-fused blocks, shared staging
  attn_fused<<<dim3(BB * NH * 16), dim3(256), 0, stream>>>(qkv, ctx);
  // 3) output projection — 128x128 (grid 512)
  gemm_bt_bias<true><<<dim3((MROWS / 128) * (DIMD / 128)), dim3(256), 0, stream>>>(
      ctx, wob, b_out, (void*)out, MROWS, DIMD, DIMD);
}

// Round 19
// 175.297 us; speedup vs baseline: 2.1897x; 2.1897x over previous
//
#include <hip/hip_runtime.h>

typedef unsigned short ushort_t;
typedef __bf16 bf16x8 __attribute__((ext_vector_type(8)));
typedef float f32x4 __attribute__((ext_vector_type(4)));

#define BB 4
#define TT 2048
#define DIMD 1024
#define NH 16
#define DK 64
#define MROWS (BB * TT)   /* 8192 */
#define NQKV (3 * DIMD)   /* 3072 */

__device__ __forceinline__ ushort_t f2b(float f) {
  __bf16 h = (__bf16)f;
  union { __bf16 h; ushort_t u; } c; c.h = h; return c.u;
}
__device__ __forceinline__ float fexp2(float x) {   // v_exp_f32: 2^x
  float r;
  asm("v_exp_f32 %0, %1" : "=v"(r) : "v"(x));
  return r;
}

// async global->LDS, 16B per lane; LDS dest is wave-uniform base + lane*16
__device__ __forceinline__ void gload_lds16(const void* g, void* l) {
  __builtin_amdgcn_global_load_lds(
      (const __attribute__((address_space(1))) void*)g,
      (__attribute__((address_space(3))) void*)l,
      16, 0, 0);
}

// f32 -> bf16 downcast, 8 elems/thread (n % 2048 == 0)
__global__ __launch_bounds__(256) void cast_f32_bf16(
    const float* __restrict__ in, ushort_t* __restrict__ out, int n)
{
  const int i = (blockIdx.x * 256 + threadIdx.x) * 8;
  if (i >= n) return;
  float4 a = *(const float4*)(in + i);
  float4 b = *(const float4*)(in + i + 4);
  ushort_t o[8];
  o[0] = f2b(a.x); o[1] = f2b(a.y); o[2] = f2b(a.z); o[3] = f2b(a.w);
  o[4] = f2b(b.x); o[5] = f2b(b.y); o[6] = f2b(b.z); o[7] = f2b(b.w);
  *(uint4*)(out + i) = *(const uint4*)o;
}

// ---------------- GEMM 128x256: DOUBLE-buffer (48KB -> 3 blocks/CU) ---------
// Round-12-verified WAR-safe schedule, counted vmcnt:
//   vmcnt(3)  -> tile t in LDS (t+1's 3 loads stay in flight)
//   s_barrier -> tile t visible to all waves
//   ds_read 8 frags (slot t&1) ; lgkmcnt(0)
//   s_barrier -> ALL waves done reading slot t&1
//   stage(t+2) -> slot t&1 (just-read slot; WAR-safe after read-drain barrier)
//   16 MFMA (setprio)
template <bool OUT_F32>
__global__ __launch_bounds__(512, 4) void gemm_bt_pipe(
    const ushort_t* __restrict__ A, const ushort_t* __restrict__ W,
    const float* __restrict__ bias, void* __restrict__ Cp,
    int M, int N, int K)
{
  __shared__ __align__(16) ushort_t As[2][128 * 32];
  __shared__ __align__(16) ushort_t Bs[2][256 * 32];

  const int tid = threadIdx.x;
  const int wave = tid >> 6, lane = tid & 63;
  const int x = blockIdx.x & 7, j = blockIdx.x >> 3;   // XCD id, local index
  const int bm = (x << 3) | (j & 7);
  const int bn = j >> 3;
  const int row0 = bm << 7, col0 = bn << 8;
  const int wm = (wave >> 2) << 6;
  const int wn = (wave & 3) << 6;
  const int fr = lane & 15;
  const int g  = lane >> 4;
  const int g4 = g << 2;
  const int csw = (g ^ (fr >> 2)) << 3;

  const int srow = lane >> 2;
  const int scol = ((lane & 3) ^ ((lane >> 4) & 3)) << 3;
  const int lbase = wave << 9;

  const ushort_t* Ag  = A + (size_t)(row0 + (wave << 4) + srow) * K + scol;
  const ushort_t* Wg0 = W + (size_t)(col0 + (wave << 4) + srow) * K + scol;
  const ushort_t* Wg1 = Wg0 + (size_t)128 * K;

#define STAGE_P(kt, buf)                                                      \
  {                                                                           \
    const size_t _k = (size_t)(kt) << 5;                                      \
    gload_lds16(Ag + _k,  &As[buf][lbase]);                                   \
    gload_lds16(Wg0 + _k, &Bs[buf][lbase]);                                   \
    gload_lds16(Wg1 + _k, &Bs[buf][4096 + lbase]);                            \
  }

  const int NT = K >> 5;
  STAGE_P(0, 0);
  STAGE_P(1, 1);

  f32x4 acc[4][4] = {};

  for (int t = 0; t < NT; ++t) {
    if (t + 1 < NT) asm volatile("s_waitcnt vmcnt(3)" ::: "memory");
    else            asm volatile("s_waitcnt vmcnt(0)" ::: "memory");
    __builtin_amdgcn_s_barrier();

    const int buf = t & 1;
    const ushort_t* as_ = As[buf];
    const ushort_t* bs_ = Bs[buf];
    bf16x8 af0 = *(const bf16x8*)&as_[(wm +      fr) * 32 + csw];
    bf16x8 af1 = *(const bf16x8*)&as_[(wm + 16 + fr) * 32 + csw];
    bf16x8 af2 = *(const bf16x8*)&as_[(wm + 32 + fr) * 32 + csw];
    bf16x8 af3 = *(const bf16x8*)&as_[(wm + 48 + fr) * 32 + csw];
    bf16x8 bw0 = *(const bf16x8*)&bs_[(wn +      fr) * 32 + csw];
    bf16x8 bw1 = *(const bf16x8*)&bs_[(wn + 16 + fr) * 32 + csw];
    bf16x8 bw2 = *(const bf16x8*)&bs_[(wn + 32 + fr) * 32 + csw];
    bf16x8 bw3 = *(const bf16x8*)&bs_[(wn + 48 + fr) * 32 + csw];
    asm volatile("s_waitcnt lgkmcnt(0)" ::: "memory");
    __builtin_amdgcn_s_barrier();          // read-drain: slot buf reusable

    if (t + 2 < NT) STAGE_P(t + 2, buf);   // DMA overlaps MFMA below

    __builtin_amdgcn_sched_barrier(0);
    __builtin_amdgcn_s_setprio(1);
    acc[0][0] = __builtin_amdgcn_mfma_f32_16x16x32_bf16(af0, bw0, acc[0][0], 0, 0, 0);
    acc[0][1] = __builtin_amdgcn_mfma_f32_16x16x32_bf16(af0, bw1, acc[0][1], 0, 0, 0);
    acc[0][2] = __builtin_amdgcn_mfma_f32_16x16x32_bf16(af0, bw2, acc[0][2], 0, 0, 0);
    acc[0][3] = __builtin_amdgcn_mfma_f32_16x16x32_bf16(af0, bw3, acc[0][3], 0, 0, 0);
    acc[1][0] = __builtin_amdgcn_mfma_f32_16x16x32_bf16(af1, bw0, acc[1][0], 0, 0, 0);
    acc[1][1] = __builtin_amdgcn_mfma_f32_16x16x32_bf16(af1, bw1, acc[1][1], 0, 0, 0);
    acc[1][2] = __builtin_amdgcn_mfma_f32_16x16x32_bf16(af1, bw2, acc[1][2], 0, 0, 0);
    acc[1][3] = __builtin_amdgcn_mfma_f32_16x16x32_bf16(af1, bw3, acc[1][3], 0, 0, 0);
    acc[2][0] = __builtin_amdgcn_mfma_f32_16x16x32_bf16(af2, bw0, acc[2][0], 0, 0, 0);
    acc[2][1] = __builtin_amdgcn_mfma_f32_16x16x32_bf16(af2, bw1, acc[2][1], 0, 0, 0);
    acc[2][2] = __builtin_amdgcn_mfma_f32_16x16x32_bf16(af2, bw2, acc[2][2], 0, 0, 0);
    acc[2][3] = __builtin_amdgcn_mfma_f32_16x16x32_bf16(af2, bw3, acc[2][3], 0, 0, 0);
    acc[3][0] = __builtin_amdgcn_mfma_f32_16x16x32_bf16(af3, bw0, acc[3][0], 0, 0, 0);
    acc[3][1] = __builtin_amdgcn_mfma_f32_16x16x32_bf16(af3, bw1, acc[3][1], 0, 0, 0);
    acc[3][2] = __builtin_amdgcn_mfma_f32_16x16x32_bf16(af3, bw2, acc[3][2], 0, 0, 0);
    acc[3][3] = __builtin_amdgcn_mfma_f32_16x16x32_bf16(af3, bw3, acc[3][3], 0, 0, 0);
    __builtin_amdgcn_s_setprio(0);
  }
#undef STAGE_P

#pragma unroll
  for (int jj = 0; jj < 4; ++jj) {
    const int col = col0 + wn + (jj << 4) + fr;
    const float bv = bias[col];
#pragma unroll
    for (int i = 0; i < 4; ++i)
#pragma unroll
      for (int r = 0; r < 4; ++r) {
        const size_t row = (size_t)(row0 + wm + (i << 4) + g4 + r);
        if constexpr (OUT_F32)
          ((float*)Cp)[row * (size_t)N + col] = acc[i][jj][r] + bv;
        else
          ((ushort_t*)Cp)[row * (size_t)N + col] = f2b(acc[i][jj][r] + bv);
      }
  }
}

// ---------------- Flash attention (EXACT round-13 kernel: 82us verified) ----
#define C1 0.18033688011112042f   /* 0.125 * log2(e) */
__global__ __launch_bounds__(512, 4) void attn_fused(
    const ushort_t* __restrict__ qkv, ushort_t* __restrict__ ctx)
{
  __shared__ __align__(16) ushort_t Qs[128 * 64];
  __shared__ __align__(16) ushort_t Ks[2][64 * 64];
  __shared__ __align__(16) ushort_t Vt[64 * 64];
  __shared__ __align__(16) ushort_t Ps[8][16 * 64];

  const int tid = threadIdx.x, wave = tid >> 6, lane = tid & 63;
  const int fr = lane & 15;
  const int g  = lane >> 4;
  const int fk = g << 3;
  const int g4 = g << 2;

  const int bid = blockIdx.x;
  const int bq  = (bid >> 3) & 7;
  const int G   = (bid & 7) | ((bid >> 6) << 3);
  const int h   = G & 15;
  const int b   = G >> 4;

  const int srl = lane >> 3;
  const int scc = ((lane & 7) ^ srl) << 3;
  const int vr  = tid >> 3;
  const int vc  = (tid & 7) << 3;
  const int rsw = (fr & 7) << 3;

  const ushort_t* Kg = qkv + (size_t)b * TT * NQKV + DIMD + h * DK;
  const ushort_t* Vg = qkv + (size_t)b * TT * NQKV + 2 * DIMD + h * DK;

#pragma unroll 1
  for (int t = 0; t < 2; ++t) {
    const int qt = t ? (15 - bq) : bq;
    const int ktmax = 2 * qt + 1;
    const int diag  = 2 * qt + (wave >> 2);
    const size_t qrow0 = (size_t)b * TT + (size_t)qt * 128;

    __syncthreads();

    const ushort_t* Qg = qkv + qrow0 * NQKV + h * DK;
#pragma unroll
    for (int pp = 0; pp < 2; ++pp) {
      const int e  = (wave << 9) + (pp << 12);
      const int rr = (e >> 6) + srl;
      gload_lds16(Qg + (size_t)rr * NQKV + scc, Qs + e);
    }
    {
      const int e  = wave << 9;
      const int rr = (wave << 3) + srl;
      gload_lds16(Kg + (size_t)rr * NQKV + scc, Ks[0] + e);
    }
    uint4 va = *(const uint4*)(Vg + (size_t)vr * NQKV + vc);
    asm volatile("s_waitcnt vmcnt(0)" ::: "memory");
    __syncthreads();

    bf16x8 aqr[2];
#pragma unroll
    for (int ks = 0; ks < 2; ++ks)
      aqr[ks] = *(const bf16x8*)&Qs[((wave << 4) + fr) * 64 + (((ks << 5) + fk) ^ rsw)];

    const int qrow = (qt << 7) + (wave << 4) + fr;
    float mrow = -1e30f, lrow = 0.f;
    f32x4 oacc[4] = {};
    int cur = 0;

    for (int kt = 0; kt <= ktmax; ++kt) {
      {
        __align__(16) ushort_t tmp[8];
        *(uint4*)tmp = va;
#pragma unroll
        for (int jj = 0; jj < 8; ++jj) {
          const int d  = vc + jj;
          const int hh = (d & 7) ^ ((d >> 3) & 7);
          Vt[d * 64 + (vr ^ (hh << 3))] = tmp[jj];
        }
      }
      if (kt < ktmax) {
        const size_t krow = (size_t)(kt + 1) << 6;
        const int e  = wave << 9;
        const int rr = (wave << 3) + srl;
        gload_lds16(Kg + (krow + rr) * NQKV + scc, Ks[cur ^ 1] + e);
        va = *(const uint4*)(Vg + (krow + vr) * NQKV + vc);
      }
      asm volatile("s_waitcnt lgkmcnt(0)" ::: "memory");
      __builtin_amdgcn_s_barrier();

      if (kt <= diag) {
        f32x4 s[4] = {};
        __builtin_amdgcn_s_setprio(1);
#pragma unroll
        for (int ks = 0; ks < 2; ++ks)
#pragma unroll
          for (int ni = 0; ni < 4; ++ni) {
            const bf16x8 bk = *(const bf16x8*)&Ks[cur][((ni << 4) + fr) * 64 + (((ks << 5) + fk) ^ rsw)];
            s[ni] = __builtin_amdgcn_mfma_f32_16x16x32_bf16(bk, aqr[ks], s[ni], 0, 0, 0);
          }
        __builtin_amdgcn_s_setprio(0);

        if (kt == diag) {
          const int kb = kt << 6;
#pragma unroll
          for (int ni = 0; ni < 4; ++ni)
#pragma unroll
            for (int r = 0; r < 4; ++r) {
              const int kc = kb + (ni << 4) + g4 + r;
              if (kc > qrow) s[ni][r] = -1e30f;
            }
        }

        float rm = -1e30f;
#pragma unroll
        for (int ni = 0; ni < 4; ++ni) {
          const float m01 = fmaxf(s[ni][0], s[ni][1]);
          const float m23 = fmaxf(s[ni][2], s[ni][3]);
          rm = fmaxf(rm, fmaxf(m01, m23));
        }
        rm = fmaxf(rm, __shfl_xor(rm, 16, 64));
        rm = fmaxf(rm, __shfl_xor(rm, 32, 64));

        if (__any(rm > mrow + 64.f)) {
          const float mn = fmaxf(mrow, rm);
          const float corr = fexp2((mrow - mn) * C1);
          mrow = mn;
          lrow *= corr;
#pragma unroll
          for (int ni = 0; ni < 4; ++ni) oacc[ni] *= corr;
        }
        const float nm2 = -mrow * C1;
        float rs = 0.f;
#pragma unroll
        for (int ni = 0; ni < 4; ++ni)
#pragma unroll
          for (int r = 0; r < 4; ++r) {
            const float pe = fexp2(fmaf(s[ni][r], C1, nm2));
            s[ni][r] = pe;
            rs += pe;
          }
        rs += __shfl_xor(rs, 16, 64);
        rs += __shfl_xor(rs, 32, 64);
        lrow += rs;

#pragma unroll
        for (int ni = 0; ni < 4; ++ni) {
          ushort_t o4[4];
#pragma unroll
          for (int r = 0; r < 4; ++r) o4[r] = f2b(s[ni][r]);
          *(uint2*)&Ps[wave][fr * 64 + (((ni << 4) + g4) ^ rsw)] = *(const uint2*)o4;
        }
        asm volatile("s_waitcnt lgkmcnt(0)" ::: "memory");
        __builtin_amdgcn_sched_barrier(0);

        __builtin_amdgcn_s_setprio(1);
#pragma unroll
        for (int ks = 0; ks < 2; ++ks) {
          const bf16x8 ap = *(const bf16x8*)&Ps[wave][fr * 64 + (((ks << 5) + fk) ^ rsw)];
#pragma unroll
          for (int ni = 0; ni < 4; ++ni) {
            const int hh = (fr & 7) ^ ((2 * ni + (fr >> 3)) & 7);
            const bf16x8 bv = *(const bf16x8*)&Vt[((ni << 4) + fr) * 64 + (((ks << 5) + fk) ^ (hh << 3))];
            oacc[ni] = __builtin_amdgcn_mfma_f32_16x16x32_bf16(bv, ap, oacc[ni], 0, 0, 0);
          }
        }
        __builtin_amdgcn_s_setprio(0);
      }

      if (kt < ktmax) {
        asm volatile("s_waitcnt vmcnt(0)" ::: "memory");
        __syncthreads();
      }
      cur ^= 1;
    }

    const float inv = 1.f / lrow;
    ushort_t* crow = ctx + (qrow0 + (wave << 4) + fr) * DIMD + h * DK;
#pragma unroll
    for (int ni = 0; ni < 4; ++ni) {
      ushort_t o4[4];
#pragma unroll
      for (int r = 0; r < 4; ++r) o4[r] = f2b(oacc[ni][r] * inv);
      *(uint2*)&crow[(ni << 4) + g4] = *(const uint2*)o4;
    }
  }
}

extern "C" void kernel_launch(void* const* d_in, const int* in_sizes, int n_in,
                              void* d_out, int out_size, void* d_ws, size_t ws_size,
                              hipStream_t stream) {
  const float* x     = (const float*)d_in[0];
  const float* w_qkv = (const float*)d_in[1];
  const float* b_qkv = (const float*)d_in[2];
  const float* w_out = (const float*)d_in[3];
  const float* b_out = (const float*)d_in[4];

  const size_t need = 36u * 1024 * 1024 * sizeof(ushort_t);   // 72 MiB
  if (ws_size < need) return;

  ushort_t* qkv = (ushort_t*)d_ws;
  ushort_t* xb  = qkv + (size_t)MROWS * NQKV;
  ushort_t* wqb = xb  + (size_t)MROWS * DIMD;
  ushort_t* wob = wqb + (size_t)NQKV * DIMD;
  ushort_t* ctx = xb;
  float*    out = (float*)d_out;

  cast_f32_bf16<<<dim3(MROWS * DIMD / 2048), dim3(256), 0, stream>>>(x, xb, MROWS * DIMD);
  cast_f32_bf16<<<dim3(NQKV * DIMD / 2048), dim3(256), 0, stream>>>(w_qkv, wqb, NQKV * DIMD);
  cast_f32_bf16<<<dim3(DIMD * DIMD / 2048), dim3(256), 0, stream>>>(w_out, wob, DIMD * DIMD);
  // 1) QKV projection — 128x256 double-buffer pipeline (48KB LDS, 3 blocks/CU)
  gemm_bt_pipe<false><<<dim3((MROWS / 128) * (NQKV / 256)), dim3(512), 0, stream>>>(
      xb, wqb, b_qkv, (void*)qkv, MROWS, NQKV, DIMD);
  // 2) causal flash attention — exact round-13 kernel (82us)
  attn_fused<<<dim3(BB * NH * 8), dim3(512), 0, stream>>>(qkv, ctx);
  // 3) output projection — same pipeline (grid 256)
  gemm_bt_pipe<true><<<dim3((MROWS / 128) * (DIMD / 256)), dim3(512), 0, stream>>>(
      ctx, wob, b_out, (void*)out, MROWS, DIMD, DIMD);
}